// Round 2
// baseline (1001.707 us; speedup 1.0000x reference)
//
#include <hip/hip_runtime.h>
#include <cstdint>
#include <cstddef>

// Problem constants
#define Bn 16
#define Tn 128
#define Dn 8192    // C*H*W
#define Fn 16      // NUM_FEAT
#define Gn 4096    // NUM_FEAT*H*W
#define MT (Bn*Tn) // 2048 rows

typedef __attribute__((ext_vector_type(8))) short short8;
typedef __attribute__((ext_vector_type(4))) float f32x4;

__device__ inline short f2bf(float f) {
    union { float f; uint32_t u; } c; c.f = f;
    uint32_t u = c.u;
    uint32_t r = (u + 0x7FFFu + ((u >> 16) & 1u)) >> 16;
    return (short)(r & 0xFFFFu);
}

__device__ inline short8 cvt8(float4 a, float4 b) {
    short8 v;
    v[0] = f2bf(a.x); v[1] = f2bf(a.y); v[2] = f2bf(a.z); v[3] = f2bf(a.w);
    v[4] = f2bf(b.x); v[5] = f2bf(b.y); v[6] = f2bf(b.z); v[7] = f2bf(b.w);
    return v;
}

// ---------------------------------------------------------------------------
// fp32 -> bf16 convert (RNE). Each thread handles 8 floats: 32B read, 16B write.
// ---------------------------------------------------------------------------
__global__ __launch_bounds__(256) void cvt_bf16_kernel(
    const float* __restrict__ src, short* __restrict__ dst, int n8)
{
    int i = blockIdx.x * 256 + threadIdx.x;
    const int stride = gridDim.x * 256;
    for (; i < n8; i += stride) {
        const float4* s = ((const float4*)src) + (size_t)i * 2;
        float4 a = s[0], b = s[1];
        ((short8*)dst)[i] = cvt8(a, b);
    }
}

// ---------------------------------------------------------------------------
// Kernel 1: q = x1 @ w1^T + b1 ; k = x2 @ w2^T + b2   (fp32)
// 512 blocks x 256 threads; each block handles 4 (b,t) rows.
// 32 groups of 8 threads: groups 0..15 -> q feature f, groups 16..31 -> k.
// 4 independent accumulators + unroll 8 for latency hiding (16 loads in flight).
// ---------------------------------------------------------------------------
__global__ __launch_bounds__(256) void qk_kernel(
    const float* __restrict__ x1, const float* __restrict__ x2,
    const float* __restrict__ w1, const float* __restrict__ b1,
    const float* __restrict__ w2, const float* __restrict__ b2,
    float* __restrict__ q, float* __restrict__ k)
{
    const int g  = threadIdx.x >> 3;   // 0..31
    const int l8 = threadIdx.x & 7;    // 0..7
    const int f  = g & 15;
    const bool isQ = (g < 16);
    const float* x = isQ ? x1 : x2;
    const float* w = (isQ ? w1 : w2) + (size_t)f * Dn;
    const float* bias = isQ ? b1 : b2;
    float* outp = isQ ? q : k;

    #pragma unroll 1
    for (int rr = 0; rr < 4; ++rr) {
        const int bt = blockIdx.x * 4 + rr;
        const float4* xr = (const float4*)(x + (size_t)bt * Dn);
        const float4* wr = (const float4*)w;
        float a0 = 0.f, a1 = 0.f, a2 = 0.f, a3 = 0.f;
        #pragma unroll 8
        for (int c = l8; c < Dn / 4; c += 8) {
            float4 xv = xr[c];
            float4 wv = wr[c];
            a0 += xv.x * wv.x; a1 += xv.y * wv.y;
            a2 += xv.z * wv.z; a3 += xv.w * wv.w;
        }
        float acc = (a0 + a1) + (a2 + a3);
        acc += __shfl_xor(acc, 4, 64);
        acc += __shfl_xor(acc, 2, 64);
        acc += __shfl_xor(acc, 1, 64);
        if (l8 == 0) outp[bt * Fn + f] = acc + bias[f];
    }
}

// ---------------------------------------------------------------------------
// Kernel 2: scores = q @ k^T per batch; attn = softmax over t (axis=1!)
// One block (128 threads) per batch; thread s owns column s.
// ---------------------------------------------------------------------------
__global__ __launch_bounds__(128) void attn_kernel(
    const float* __restrict__ q, const float* __restrict__ k,
    float* __restrict__ attn)
{
    __shared__ float qs[Tn * 17];
    const int b = blockIdx.x;
    const int tid = threadIdx.x;   // = s, 0..127

    for (int i = tid; i < Tn * Fn; i += 128)
        qs[(i >> 4) * 17 + (i & 15)] = q[b * Tn * Fn + i];
    __syncthreads();

    float kr[16];
    #pragma unroll
    for (int f = 0; f < 16; ++f) kr[f] = k[b * Tn * Fn + tid * Fn + f];

    float m = -1e30f, sum = 0.f;
    #pragma unroll 1
    for (int t = 0; t < Tn; ++t) {
        float sc = 0.f;
        #pragma unroll
        for (int f = 0; f < 16; ++f) sc += qs[t * 17 + f] * kr[f];
        if (sc > m) { sum = sum * __expf(m - sc) + 1.f; m = sc; }
        else        { sum += __expf(sc - m); }
    }
    const float inv = 1.f / sum;
    float* ap = attn + (size_t)b * Tn * Tn;
    #pragma unroll 1
    for (int t = 0; t < Tn; ++t) {
        float sc = 0.f;
        #pragma unroll
        for (int f = 0; f < 16; ++f) sc += qs[t * 17 + f] * kr[f];
        ap[t * Tn + tid] = __expf(sc - m) * inv;  // coalesced across s
    }
}

// ---------------------------------------------------------------------------
// Kernel 3: v = x1b @ w3b^T + b3 — bf16 MFMA GEMM, m97 structure.
// A [2048,8192] bf16, Bw [4096,8192] bf16, both row-major.
// 128x128 C-tile, BK=32, unpadded LDS [128][32] (global_load_lds layout:
// wave-uniform base + lane*16B == row-major [row][col8] with 4 lanes/row).
// ---------------------------------------------------------------------------
#define BK 32

__global__ __launch_bounds__(256) void gemm_v_kernel(
    const short* __restrict__ A, const short* __restrict__ Bw,
    const float* __restrict__ bias, float* __restrict__ C)
{
    __shared__ __attribute__((aligned(16))) short As[128 * BK];
    __shared__ __attribute__((aligned(16))) short Bs[128 * BK];

    const int tid = threadIdx.x;
    const int m0 = blockIdx.y * 128;
    const int n0 = blockIdx.x * 128;
    const int wave = tid >> 6, lane = tid & 63;
    const int wm = (wave >> 1) * 64, wn = (wave & 1) * 64;
    const int quad = lane >> 4, r = lane & 15;

    // Staging: wave w stages rows [w*32, w*32+32) of A and B, 2 insts each.
    // lane offset within wave's 16-row chunk: row=lane>>2, col8=(lane&3)*8
    // -> LDS byte offset = wave*2048 + lane*16 (the required lane-linear form).
    const int srow = wave * 32 + (lane >> 2);
    const int scol = (lane & 3) * 8;
    const short* gA = A  + (size_t)(m0 + srow) * Dn + scol;
    const short* gB = Bw + (size_t)(n0 + srow) * Dn + scol;
    short* lA = &As[srow * BK + scol];
    short* lB = &Bs[srow * BK + scol];

    f32x4 acc[4][4] = {};

    #pragma unroll 1
    for (int k0 = 0; k0 < Dn; k0 += BK) {
        __syncthreads();
        __builtin_amdgcn_global_load_lds(
            (const __attribute__((address_space(1))) void*)(gA + k0),
            (__attribute__((address_space(3))) void*)lA, 16, 0, 0);
        __builtin_amdgcn_global_load_lds(
            (const __attribute__((address_space(1))) void*)(gA + k0 + (size_t)16 * Dn),
            (__attribute__((address_space(3))) void*)(lA + 16 * BK), 16, 0, 0);
        __builtin_amdgcn_global_load_lds(
            (const __attribute__((address_space(1))) void*)(gB + k0),
            (__attribute__((address_space(3))) void*)lB, 16, 0, 0);
        __builtin_amdgcn_global_load_lds(
            (const __attribute__((address_space(1))) void*)(gB + k0 + (size_t)16 * Dn),
            (__attribute__((address_space(3))) void*)(lB + 16 * BK), 16, 0, 0);
        __syncthreads();

        short8 af[4], bf[4];
        #pragma unroll
        for (int i = 0; i < 4; ++i)
            af[i] = *(const short8*)&As[(wm + i * 16 + r) * BK + quad * 8];
        #pragma unroll
        for (int j = 0; j < 4; ++j)
            bf[j] = *(const short8*)&Bs[(wn + j * 16 + r) * BK + quad * 8];

        #pragma unroll
        for (int i = 0; i < 4; ++i)
            #pragma unroll
            for (int j = 0; j < 4; ++j)
                acc[i][j] = __builtin_amdgcn_mfma_f32_16x16x32_bf16(
                    af[i], bf[j], acc[i][j], 0, 0, 0);
    }

    // Epilogue: C/D layout col=lane&15 (n), row=quad*4+reg (m). Add bias, fp32 out.
    #pragma unroll
    for (int j = 0; j < 4; ++j) {
        const int col = n0 + wn + j * 16 + r;
        const float bv = bias[col];
        #pragma unroll
        for (int i = 0; i < 4; ++i) {
            #pragma unroll
            for (int reg = 0; reg < 4; ++reg) {
                const int rowg = m0 + wm + i * 16 + quad * 4 + reg;
                C[(size_t)rowg * Gn + col] = acc[i][j][reg] + bv;
            }
        }
    }
}

// ---------------------------------------------------------------------------
// Kernel 4: out[b,t,g] = sum_s attn[b,t,s] * v[b,s,g]
// attn tile stored TRANSPOSED in LDS (stride 20 floats, 16B aligned) so each
// s-iteration is 4 broadcast ds_read_b128 instead of 16 ds_read_b32.
// ---------------------------------------------------------------------------
__global__ __launch_bounds__(256) void out_kernel(
    const float* __restrict__ attn, const float* __restrict__ v,
    float* __restrict__ out)
{
    __shared__ __attribute__((aligned(16))) float a_s[Tn * 20];
    const int b = blockIdx.z;
    const int t0 = blockIdx.y * 16;
    const int g = blockIdx.x * 256 + threadIdx.x;

    const float* ab = attn + (size_t)b * Tn * Tn + (size_t)t0 * Tn;
    for (int i = threadIdx.x; i < 16 * Tn; i += 256) {
        const int s = i & 127, tt = i >> 7;
        a_s[s * 20 + tt] = ab[tt * Tn + s];     // coalesced global read
    }
    __syncthreads();

    float acc[16];
    #pragma unroll
    for (int tt = 0; tt < 16; ++tt) acc[tt] = 0.f;

    const float* vb = v + (size_t)b * Tn * Gn + g;
    const float4* as4 = (const float4*)a_s;
    #pragma unroll 4
    for (int s = 0; s < Tn; ++s) {
        const float vs = vb[(size_t)s * Gn];
        float4 a0 = as4[s * 5 + 0], a1 = as4[s * 5 + 1];
        float4 a2 = as4[s * 5 + 2], a3 = as4[s * 5 + 3];
        acc[ 0] += a0.x * vs; acc[ 1] += a0.y * vs; acc[ 2] += a0.z * vs; acc[ 3] += a0.w * vs;
        acc[ 4] += a1.x * vs; acc[ 5] += a1.y * vs; acc[ 6] += a1.z * vs; acc[ 7] += a1.w * vs;
        acc[ 8] += a2.x * vs; acc[ 9] += a2.y * vs; acc[10] += a2.z * vs; acc[11] += a2.w * vs;
        acc[12] += a3.x * vs; acc[13] += a3.y * vs; acc[14] += a3.z * vs; acc[15] += a3.w * vs;
    }

    float* ob = out + (size_t)b * Tn * Gn + (size_t)t0 * Gn + g;
    #pragma unroll
    for (int tt = 0; tt < 16; ++tt) ob[(size_t)tt * Gn] = acc[tt];
}

// ---------------------------------------------------------------------------
extern "C" void kernel_launch(void* const* d_in, const int* in_sizes, int n_in,
                              void* d_out, int out_size, void* d_ws, size_t ws_size,
                              hipStream_t stream)
{
    const float* x1 = (const float*)d_in[0];
    const float* x2 = (const float*)d_in[1];
    const float* w1 = (const float*)d_in[2];
    const float* b1 = (const float*)d_in[3];
    const float* w2 = (const float*)d_in[4];
    const float* b2 = (const float*)d_in[5];
    const float* w3 = (const float*)d_in[6];
    const float* b3 = (const float*)d_in[7];
    float* out = (float*)d_out;

    // Workspace layout:
    // fp32: q[32K] k[32K] attn[256K] v[8.39M]   then bf16: x1b[16.8M] w3b[33.6M]
    float* q    = (float*)d_ws;
    float* k    = q + MT * Fn;
    float* attn = k + MT * Fn;
    float* v    = attn + (size_t)Bn * Tn * Tn;
    short* x1b  = (short*)(v + (size_t)MT * Gn);
    short* w3b  = x1b + (size_t)MT * Dn;          // total ~135.5 MB

    cvt_bf16_kernel<<<2048, 256, 0, stream>>>(x1, x1b, MT * Dn / 8);
    cvt_bf16_kernel<<<2048, 256, 0, stream>>>(w3, w3b, Gn * Dn / 8);
    qk_kernel<<<512, 256, 0, stream>>>(x1, x2, w1, b1, w2, b2, q, k);
    attn_kernel<<<Bn, 128, 0, stream>>>(q, k, attn);
    gemm_v_kernel<<<dim3(Gn / 128, MT / 128), 256, 0, stream>>>(x1b, w3b, b3, v);
    out_kernel<<<dim3(Gn / 256, Tn / 16, Bn), 256, 0, stream>>>(attn, v, out);
}

// Round 3
// 604.874 us; speedup vs baseline: 1.6561x; 1.6561x over previous
//
#include <hip/hip_runtime.h>
#include <cstdint>
#include <cstddef>

// Problem constants
#define Bn 16
#define Tn 128
#define Dn 8192    // C*H*W
#define Fn 16      // NUM_FEAT
#define Gn 4096    // NUM_FEAT*H*W
#define MT (Bn*Tn) // 2048 rows

typedef __attribute__((ext_vector_type(8))) short short8;
typedef __attribute__((ext_vector_type(4))) float f32x4;

__device__ inline short f2bf(float f) {
    union { float f; uint32_t u; } c; c.f = f;
    uint32_t u = c.u;
    uint32_t r = (u + 0x7FFFu + ((u >> 16) & 1u)) >> 16;
    return (short)(r & 0xFFFFu);
}

__device__ inline short8 cvt8(float4 a, float4 b) {
    short8 v;
    v[0] = f2bf(a.x); v[1] = f2bf(a.y); v[2] = f2bf(a.z); v[3] = f2bf(a.w);
    v[4] = f2bf(b.x); v[5] = f2bf(b.y); v[6] = f2bf(b.z); v[7] = f2bf(b.w);
    return v;
}

// ---------------------------------------------------------------------------
// Fused fp32->bf16 convert for x1 and w3 (one launch, grid-stride).
// ---------------------------------------------------------------------------
#define N8_X1 (MT * Dn / 8)   // 2,097,152
#define N8_W3 ((size_t)Gn * Dn / 8)   // 4,194,304

__global__ __launch_bounds__(256) void cvt2_kernel(
    const float* __restrict__ x1, const float* __restrict__ w3,
    short* __restrict__ x1b, short* __restrict__ w3b)
{
    const size_t total = N8_X1 + N8_W3;
    size_t i = (size_t)blockIdx.x * 256 + threadIdx.x;
    const size_t stride = (size_t)gridDim.x * 256;
    for (; i < total; i += stride) {
        if (i < N8_X1) {
            const float4* s = ((const float4*)x1) + i * 2;
            ((short8*)x1b)[i] = cvt8(s[0], s[1]);
        } else {
            const size_t j = i - N8_X1;
            const float4* s = ((const float4*)w3) + j * 2;
            ((short8*)w3b)[j] = cvt8(s[0], s[1]);
        }
    }
}

// ---------------------------------------------------------------------------
// qk skinny GEMM: q = x1b @ w1^T + b1 (bf16 A), k = x2 @ w2^T + b2 (inline cvt).
// Grid 256 blocks x 256 threads. Block = (16-row m-tile, q-or-k).
// Wave w handles K-slice [w*2048, (w+1)*2048): fragments loaded DIRECTLY from
// global (A-frag layout: m=lane&15 row, k=quad*8+j -> one 16B short8 per lane,
// 64B per matrix row per instruction = full cache lines). LDS reduce over waves.
// ---------------------------------------------------------------------------
__global__ __launch_bounds__(256) void qk_gemm_kernel(
    const short* __restrict__ x1b, const float* __restrict__ x2,
    const float* __restrict__ w1, const float* __restrict__ w2,
    const float* __restrict__ b1, const float* __restrict__ b2,
    float* __restrict__ q, float* __restrict__ k)
{
    __shared__ float red[4][16][16];
    const int tid = threadIdx.x;
    const int tile = blockIdx.x >> 1;
    const int isK  = blockIdx.x & 1;
    const int m0 = tile * 16;
    const int wave = tid >> 6, lane = tid & 63;
    const int quad = lane >> 4, r = lane & 15;
    const int kbase = wave * (Dn / 4);   // 2048

    f32x4 acc = {};

    if (!isK) {
        const short* ap = x1b + (size_t)(m0 + r) * Dn + kbase + quad * 8;
        const float* bp = w1 + (size_t)r * Dn + kbase + quad * 8;
        #pragma unroll 4
        for (int it = 0; it < 64; ++it) {
            short8 af = *(const short8*)(ap + it * 32);
            const float4* b4 = (const float4*)(bp + it * 32);
            short8 bf = cvt8(b4[0], b4[1]);
            acc = __builtin_amdgcn_mfma_f32_16x16x32_bf16(af, bf, acc, 0, 0, 0);
        }
    } else {
        const float* apf = x2 + (size_t)(m0 + r) * Dn + kbase + quad * 8;
        const float* bp  = w2 + (size_t)r * Dn + kbase + quad * 8;
        #pragma unroll 4
        for (int it = 0; it < 64; ++it) {
            const float4* a4 = (const float4*)(apf + it * 32);
            short8 af = cvt8(a4[0], a4[1]);
            const float4* b4 = (const float4*)(bp + it * 32);
            short8 bf = cvt8(b4[0], b4[1]);
            acc = __builtin_amdgcn_mfma_f32_16x16x32_bf16(af, bf, acc, 0, 0, 0);
        }
    }

    // C/D: col(n=f)=lane&15, row(m)=quad*4+reg
    #pragma unroll
    for (int reg = 0; reg < 4; ++reg)
        red[wave][quad * 4 + reg][r] = acc[reg];
    __syncthreads();

    const int m = tid >> 4, f = tid & 15;
    float s = red[0][m][f] + red[1][m][f] + red[2][m][f] + red[3][m][f];
    s += (isK ? b2 : b1)[f];
    (isK ? k : q)[(m0 + m) * Fn + f] = s;
}

// ---------------------------------------------------------------------------
// attn: scores = q @ k^T per batch; softmax over t (axis=1!). Output bf16.
// ---------------------------------------------------------------------------
__global__ __launch_bounds__(128) void attn_kernel(
    const float* __restrict__ q, const float* __restrict__ k,
    short* __restrict__ attn16)
{
    __shared__ float qs[Tn * 17];
    const int b = blockIdx.x;
    const int tid = threadIdx.x;   // = s

    for (int i = tid; i < Tn * Fn; i += 128)
        qs[(i >> 4) * 17 + (i & 15)] = q[b * Tn * Fn + i];
    __syncthreads();

    float kr[16];
    #pragma unroll
    for (int f = 0; f < 16; ++f) kr[f] = k[b * Tn * Fn + tid * Fn + f];

    float m = -1e30f, sum = 0.f;
    #pragma unroll 1
    for (int t = 0; t < Tn; ++t) {
        float sc = 0.f;
        #pragma unroll
        for (int f = 0; f < 16; ++f) sc += qs[t * 17 + f] * kr[f];
        if (sc > m) { sum = sum * __expf(m - sc) + 1.f; m = sc; }
        else        { sum += __expf(sc - m); }
    }
    const float inv = 1.f / sum;
    short* ap = attn16 + (size_t)b * Tn * Tn;
    #pragma unroll 1
    for (int t = 0; t < Tn; ++t) {
        float sc = 0.f;
        #pragma unroll
        for (int f = 0; f < 16; ++f) sc += qs[t * 17 + f] * kr[f];
        ap[t * Tn + tid] = f2bf(__expf(sc - m) * inv);
    }
}

// ---------------------------------------------------------------------------
// Big GEMM, operands swapped to emit v^T directly:
// vT[g][bt] = sum_d w3b[g][d] * x1b[bt][d] + b3[g], stored bf16.
// A = w3b [4096,8192], B = x1b [2048,8192]. m97 structure, BK=32.
// ---------------------------------------------------------------------------
#define BK 32

__global__ __launch_bounds__(256) void gemm_v_kernel(
    const short* __restrict__ A, const short* __restrict__ Bw,
    const float* __restrict__ bias, short* __restrict__ vT)
{
    __shared__ __attribute__((aligned(16))) short As[128 * BK];
    __shared__ __attribute__((aligned(16))) short Bs[128 * BK];

    const int tid = threadIdx.x;
    const int m0 = blockIdx.y * 128;   // g dim (4096)
    const int n0 = blockIdx.x * 128;   // bt dim (2048)
    const int wave = tid >> 6, lane = tid & 63;
    const int wm = (wave >> 1) * 64, wn = (wave & 1) * 64;
    const int quad = lane >> 4, r = lane & 15;

    const int srow = wave * 32 + (lane >> 2);
    const int scol = (lane & 3) * 8;
    const short* gA = A  + (size_t)(m0 + srow) * Dn + scol;
    const short* gB = Bw + (size_t)(n0 + srow) * Dn + scol;
    short* lA = &As[srow * BK + scol];
    short* lB = &Bs[srow * BK + scol];

    f32x4 acc[4][4] = {};

    #pragma unroll 1
    for (int k0 = 0; k0 < Dn; k0 += BK) {
        __syncthreads();
        __builtin_amdgcn_global_load_lds(
            (const __attribute__((address_space(1))) void*)(gA + k0),
            (__attribute__((address_space(3))) void*)lA, 16, 0, 0);
        __builtin_amdgcn_global_load_lds(
            (const __attribute__((address_space(1))) void*)(gA + k0 + (size_t)16 * Dn),
            (__attribute__((address_space(3))) void*)(lA + 16 * BK), 16, 0, 0);
        __builtin_amdgcn_global_load_lds(
            (const __attribute__((address_space(1))) void*)(gB + k0),
            (__attribute__((address_space(3))) void*)lB, 16, 0, 0);
        __builtin_amdgcn_global_load_lds(
            (const __attribute__((address_space(1))) void*)(gB + k0 + (size_t)16 * Dn),
            (__attribute__((address_space(3))) void*)(lB + 16 * BK), 16, 0, 0);
        __syncthreads();

        short8 af[4], bf[4];
        #pragma unroll
        for (int i = 0; i < 4; ++i)
            af[i] = *(const short8*)&As[(wm + i * 16 + r) * BK + quad * 8];
        #pragma unroll
        for (int j = 0; j < 4; ++j)
            bf[j] = *(const short8*)&Bs[(wn + j * 16 + r) * BK + quad * 8];

        #pragma unroll
        for (int i = 0; i < 4; ++i)
            #pragma unroll
            for (int j = 0; j < 4; ++j)
                acc[i][j] = __builtin_amdgcn_mfma_f32_16x16x32_bf16(
                    af[i], bf[j], acc[i][j], 0, 0, 0);
    }

    // C/D: col(n=bt)=lane&15 group, row(m=g)=quad*4+reg. bias per row. bf16 out.
    #pragma unroll
    for (int i = 0; i < 4; ++i) {
        #pragma unroll
        for (int reg = 0; reg < 4; ++reg) {
            const int rowg = m0 + wm + i * 16 + quad * 4 + reg;
            const float bv = bias[rowg];
            #pragma unroll
            for (int j = 0; j < 4; ++j) {
                const int col = n0 + wn + j * 16 + r;
                vT[(size_t)rowg * MT + col] = f2bf(acc[i][j][reg] + bv);
            }
        }
    }
}

// ---------------------------------------------------------------------------
// out GEMM per batch: out[t][g] = sum_s attn[t][s] * vT[g][s].
// A = attn16[b] [128x128] bf16, B = vT[.,b*128..] [4096x128-slice] bf16.
// M=128(t), N=128-tile of 4096(g), K=128(s). 4 K-iters, same staging structure.
// ---------------------------------------------------------------------------
__global__ __launch_bounds__(256) void out_gemm_kernel(
    const short* __restrict__ attn16, const short* __restrict__ vT,
    float* __restrict__ out)
{
    __shared__ __attribute__((aligned(16))) short As[128 * BK];
    __shared__ __attribute__((aligned(16))) short Bs[128 * BK];

    const int tid = threadIdx.x;
    const int b  = blockIdx.y;
    const int n0 = blockIdx.x * 128;   // g dim
    const int wave = tid >> 6, lane = tid & 63;
    const int wm = (wave >> 1) * 64, wn = (wave & 1) * 64;
    const int quad = lane >> 4, r = lane & 15;

    const int srow = wave * 32 + (lane >> 2);
    const int scol = (lane & 3) * 8;
    const short* gA = attn16 + (size_t)b * Tn * Tn + srow * Tn + scol;       // t rows, stride 128
    const short* gB = vT + (size_t)(n0 + srow) * MT + b * Tn + scol;         // g rows, stride 2048
    short* lA = &As[srow * BK + scol];
    short* lB = &Bs[srow * BK + scol];

    f32x4 acc[4][4] = {};

    #pragma unroll 1
    for (int k0 = 0; k0 < Tn; k0 += BK) {
        __syncthreads();
        __builtin_amdgcn_global_load_lds(
            (const __attribute__((address_space(1))) void*)(gA + k0),
            (__attribute__((address_space(3))) void*)lA, 16, 0, 0);
        __builtin_amdgcn_global_load_lds(
            (const __attribute__((address_space(1))) void*)(gA + k0 + 16 * Tn),
            (__attribute__((address_space(3))) void*)(lA + 16 * BK), 16, 0, 0);
        __builtin_amdgcn_global_load_lds(
            (const __attribute__((address_space(1))) void*)(gB + k0),
            (__attribute__((address_space(3))) void*)lB, 16, 0, 0);
        __builtin_amdgcn_global_load_lds(
            (const __attribute__((address_space(1))) void*)(gB + k0 + (size_t)16 * MT),
            (__attribute__((address_space(3))) void*)(lB + 16 * BK), 16, 0, 0);
        __syncthreads();

        short8 af[4], bf[4];
        #pragma unroll
        for (int i = 0; i < 4; ++i)
            af[i] = *(const short8*)&As[(wm + i * 16 + r) * BK + quad * 8];
        #pragma unroll
        for (int j = 0; j < 4; ++j)
            bf[j] = *(const short8*)&Bs[(wn + j * 16 + r) * BK + quad * 8];

        #pragma unroll
        for (int i = 0; i < 4; ++i)
            #pragma unroll
            for (int j = 0; j < 4; ++j)
                acc[i][j] = __builtin_amdgcn_mfma_f32_16x16x32_bf16(
                    af[i], bf[j], acc[i][j], 0, 0, 0);
    }

    // C/D: row(m=t)=quad*4+reg, col(n=g)=r group. fp32 out [b][t][g].
    #pragma unroll
    for (int j = 0; j < 4; ++j) {
        const int col = n0 + wn + j * 16 + r;
        #pragma unroll
        for (int i = 0; i < 4; ++i) {
            #pragma unroll
            for (int reg = 0; reg < 4; ++reg) {
                const int rowt = wm + i * 16 + quad * 4 + reg;
                out[((size_t)(b * Tn + rowt)) * Gn + col] = acc[i][j][reg];
            }
        }
    }
}

// ---------------------------------------------------------------------------
extern "C" void kernel_launch(void* const* d_in, const int* in_sizes, int n_in,
                              void* d_out, int out_size, void* d_ws, size_t ws_size,
                              hipStream_t stream)
{
    const float* x1 = (const float*)d_in[0];
    const float* x2 = (const float*)d_in[1];
    const float* w1 = (const float*)d_in[2];
    const float* b1 = (const float*)d_in[3];
    const float* w2 = (const float*)d_in[4];
    const float* b2 = (const float*)d_in[5];
    const float* w3 = (const float*)d_in[6];
    const float* b3 = (const float*)d_in[7];
    float* out = (float*)d_out;

    // Workspace: q,k fp32; attn16, vT, x1b, w3b bf16. Total ~118 MB.
    float* q      = (float*)d_ws;
    float* k      = q + MT * Fn;
    short* attn16 = (short*)(k + MT * Fn);
    short* vT     = attn16 + (size_t)Bn * Tn * Tn;
    short* x1b    = vT + (size_t)Gn * MT;
    short* w3b    = x1b + (size_t)MT * Dn;

    cvt2_kernel<<<4096, 256, 0, stream>>>(x1, w3, x1b, w3b);
    qk_gemm_kernel<<<256, 256, 0, stream>>>(x1b, x2, w1, w2, b1, b2, q, k);
    attn_kernel<<<Bn, 128, 0, stream>>>(q, k, attn16);
    gemm_v_kernel<<<dim3(MT / 128, Gn / 128), 256, 0, stream>>>(w3b, x1b, b3, vT);
    out_gemm_kernel<<<dim3(Gn / 128, Bn), 256, 0, stream>>>(attn16, vT, out);
}